// Round 4
// baseline (308.241 us; speedup 1.0000x reference)
//
#include <hip/hip_runtime.h>

// ---------------------------------------------------------------------------
// EnsembleTransitionMLP: fused 4-layer MLP over 50 ensembles, bf16 MFMA.
// Round 4:
//  - 32x32x16 MFMA (2382 TF ubench vs 2075 for 16x16; half the instructions).
//  - BM=64, 256 thr, 4 waves (wf=feat strip of 64); per-wave 2x2 tiles of
//    32x32, acc=64 AGPR. hT = 32KB LDS -> 3 blocks/CU at VGPR<=170.
//  - depth-4 circular register prefetch ring on weight fragments, fully
//    unrolled K-loop (launch_bounds(256,3) frees 170 regs/wave; R3 failed
//    because acc+operands exactly filled the 128-reg budget).
// Fragment layouts (32x32x16 bf16):
//   A: lane l holds A[m=l&31][k=(l>>5)*8+j]   (weights, used as W^T)
//   B: lane l holds B[k=(l>>5)*8+j][n=l&31]   (h^T: k=feat, n=batch)
//   C/D: reg r: row=(r&3)+8*(r>>2)+4*(l>>5), col=l&31
// ---------------------------------------------------------------------------

typedef __attribute__((ext_vector_type(8))) short short8;
typedef __attribute__((ext_vector_type(16))) float floatx16;

#define NE 50
#define NB 8192
#define OUT_NS_ELEMS (NB * NE * 32)

__device__ __forceinline__ unsigned short f2bf_rne(float x) {
  unsigned u = __float_as_uint(x);
  u += 0x7fffu + ((u >> 16) & 1u);
  return (unsigned short)(u >> 16);
}
__device__ __forceinline__ float bf2f(unsigned short b) {
  return __uint_as_float(((unsigned)b) << 16);
}
__device__ __forceinline__ floatx16 mfma32(short8 a, short8 b, floatx16 c) {
  return __builtin_amdgcn_mfma_f32_32x32x16_bf16(a, b, c, 0, 0, 0);
}
// pack two f32 -> one dword of bf16 pair, round-half-up
__device__ __forceinline__ unsigned pack_bf2(float lo, float hi) {
  unsigned u0 = __float_as_uint(lo) + 0x8000u;
  unsigned u1 = __float_as_uint(hi) + 0x8000u;
  return __builtin_amdgcn_perm(u1, u0, 0x07060302u);  // [u0.hi16, u1.hi16]
}

// ---------------- dtype detection ----------------
__global__ void k_detect(const unsigned* __restrict__ w2raw, int* __restrict__ flag) {
  __shared__ int s_bad;
  if (threadIdx.x == 0) s_bad = 0;
  __syncthreads();
  bool bad = false;
  for (int i = threadIdx.x; i < 2048; i += 256) {
    unsigned word = w2raw[i * 797];
    unsigned short lo = (unsigned short)(word & 0xFFFFu);
    float f = bf2f(lo);
    if (!(fabsf(f) < 16.0f)) bad = true;
    if (lo == 0) bad = true;
  }
  if (bad) s_bad = 1;
  __syncthreads();
  if (threadIdx.x == 0) *flag = s_bad ? 0 : 1;  // 1 => bf16 inputs
}

__device__ __forceinline__ unsigned short load_bf(const void* p, long i, bool isbf) {
  if (isbf) return ((const unsigned short*)p)[i];
  return f2bf_rne(((const float*)p)[i]);
}
__device__ __forceinline__ float load_f(const void* p, long i, bool isbf) {
  if (isbf) return bf2f(((const unsigned short*)p)[i]);
  return ((const float*)p)[i];
}

// ---------------- mega pack ----------------
// W pack (A-frag units, 32x32x16): unit u = kstep*NFT + ft; lane l, j:
//   feat = ft*32 + (l&31); k = kstep*16 + (l>>5)*8 + j; elem = W[e][k][feat]
// One block packs a 32-k-row panel (2 ksteps) of one (matrix, e).
__device__ void pack_w_panel(const void* __restrict__ src, unsigned short* __restrict__ dst,
                             bool isbf, int e, int kt, int K, int N, int NFT, int perE,
                             unsigned short* lds) {
  const int t = threadIdx.x;
  const int Npad = NFT * 32;
  const int NP = Npad + 10;
  for (int idx = t; idx < 32 * Npad; idx += 256) {
    int r = idx / Npad, c = idx - r * Npad;
    int k = kt * 32 + r;
    unsigned short v = 0;
    if (k < K && c < N) v = load_bf(src, (long)(e * K + k) * N + c, isbf);
    lds[r * NP + c] = v;
  }
  __syncthreads();
  for (int u = t; u < NFT * 128; u += 256) {
    int l = u & 63, ft = (u >> 6) % NFT, ksl = (u >> 6) / NFT;
    int feat = ft * 32 + (l & 31);
    int rbase = ksl * 16 + (l >> 5) * 8;
    unsigned v[4];
#pragma unroll
    for (int p = 0; p < 4; ++p) {
      unsigned lo = lds[(rbase + 2 * p) * NP + feat];
      unsigned hi = lds[(rbase + 2 * p + 1) * NP + feat];
      v[p] = lo | (hi << 16);
    }
    long off = (long)e * perE + ((long)(((kt * 2 + ksl) * NFT + ft) * 64 + l)) * 8;
    *(uint4*)(dst + off) = make_uint4(v[0], v[1], v[2], v[3]);
  }
}

__global__ void k_pack(const void* __restrict__ state, const void* __restrict__ action,
                       const void* __restrict__ W1, const void* __restrict__ W2,
                       const void* __restrict__ W3, const void* __restrict__ W4,
                       const void* __restrict__ b1, const void* __restrict__ b2,
                       const void* __restrict__ b3, const void* __restrict__ b4,
                       const int* __restrict__ flag,
                       unsigned short* __restrict__ saP, unsigned short* __restrict__ w1P,
                       unsigned short* __restrict__ w2P, unsigned short* __restrict__ w3P,
                       unsigned short* __restrict__ w4P, float* __restrict__ biasP) {
  __shared__ unsigned short lds[32 * 266];  // 17,024 B (max NP=266)
  const bool isbf = (*flag != 0);
  const int b = blockIdx.x;
  if (b < 400) {
    pack_w_panel(W2, w2P, isbf, b >> 3, b & 7, 256, 256, 8, 65536, lds);
  } else if (b < 800) {
    int bb = b - 400;
    pack_w_panel(W3, w3P, isbf, bb >> 3, bb & 7, 256, 256, 8, 65536, lds);
  } else if (b < 900) {
    int bb = b - 800;
    pack_w_panel(W1, w1P, isbf, bb >> 1, bb & 1, 40, 256, 8, 16384, lds);
  } else if (b < 1300) {
    int bb = b - 900;
    pack_w_panel(W4, w4P, isbf, bb >> 3, bb & 7, 256, 33, 2, 16384, lds);
  } else if (b < 1556) {
    // sa pack (B-frag units): unit u = btile*4 + kstep; lane l, j:
    //   batch = btile*32 + (l&31); k = kstep*16 + (l>>5)*8 + j  (K pad 40->64)
    int gp = (b - 1300) * 256 + threadIdx.x;  // < 65536 lane-parts
    int l = gp & 63, u = gp >> 6;
    int batch = (u >> 2) * 32 + (l & 31);
    int k0 = (u & 3) * 16 + (l >> 5) * 8;
    int kb8 = k0 >> 3;
    unsigned v[4] = {0u, 0u, 0u, 0u};
    if (kb8 < 4) {
#pragma unroll
      for (int p = 0; p < 4; ++p) {
        unsigned lo = load_bf(state, (long)batch * 32 + kb8 * 8 + 2 * p, isbf);
        unsigned hi = load_bf(state, (long)batch * 32 + kb8 * 8 + 2 * p + 1, isbf);
        v[p] = lo | (hi << 16);
      }
    } else if (kb8 == 4) {
#pragma unroll
      for (int p = 0; p < 4; ++p) {
        unsigned lo = load_bf(action, (long)batch * 8 + 2 * p, isbf);
        unsigned hi = load_bf(action, (long)batch * 8 + 2 * p + 1, isbf);
        v[p] = lo | (hi << 16);
      }
    }
    *(uint4*)(saP + (long)gp * 8) = make_uint4(v[0], v[1], v[2], v[3]);
  } else {
    // bias: per e: [b1(256)][b2(256)][b3(256)][b4(64, 33 real + pad)]
    int gid = (b - 1556) * 256 + threadIdx.x;
    if (gid < NE * 832) {
      int e = gid / 832, r = gid - e * 832;
      float v = 0.0f;
      if (r < 256)      v = load_f(b1, e * 256 + r,         isbf);
      else if (r < 512) v = load_f(b2, e * 256 + (r - 256), isbf);
      else if (r < 768) v = load_f(b3, e * 256 + (r - 512), isbf);
      else { int q = r - 768; if (q < 33) v = load_f(b4, e * 33 + q, isbf); }
      biasP[gid] = v;
    }
  }
}

// ---------------- fused MLP ----------------
// hT in LDS (32KB), B-frag units: unit(kstep 0..15, bt 0..1) = kstep*2+bt;
// short addr = unit*512 + l*8 + j.
// store: acc reg r of tile (FT, BT): feat=FT*32+(r&3)+8*(r>>2)+4*(l>>5),
// batch=BT*32+(l&31) -> per quad q one ds_write_b64 at
//   ((FT*2+(q>>1))*2 + BT)*512 + ((q&1)*32 + (l&31))*8 + 4*(l>>5)

__device__ __forceinline__ void store_tile(const floatx16& acc, unsigned short* hT,
                                           int FT, int BT, int li31, int lo5) {
#pragma unroll
  for (int q = 0; q < 4; ++q) {
    float v0 = fmaxf(acc[4 * q + 0], 0.0f);
    float v1 = fmaxf(acc[4 * q + 1], 0.0f);
    float v2 = fmaxf(acc[4 * q + 2], 0.0f);
    float v3 = fmaxf(acc[4 * q + 3], 0.0f);
    unsigned d0 = pack_bf2(v0, v1);
    unsigned d1 = pack_bf2(v2, v3);
    int saddr = ((FT * 2 + (q >> 1)) * 2 + BT) * 512 + ((q & 1) * 32 + li31) * 8 + 4 * lo5;
    *(unsigned long long*)(hT + saddr) =
        (unsigned long long)d0 | ((unsigned long long)d1 << 32);
  }
}

__device__ __forceinline__ void bias_init2x2(floatx16 (&acc)[2][2], const float* br,
                                             int wf, int lo5) {
#pragma unroll
  for (int i = 0; i < 2; ++i) {
#pragma unroll
    for (int q = 0; q < 4; ++q) {
      const float4 bq = *(const float4*)(br + (wf * 2 + i) * 32 + q * 8 + lo5 * 4);
#pragma unroll
      for (int o = 0; o < 2; ++o) {
        acc[i][o][4 * q + 0] = bq.x;
        acc[i][o][4 * q + 1] = bq.y;
        acc[i][o][4 * q + 2] = bq.z;
        acc[i][o][4 * q + 3] = bq.w;
      }
    }
  }
}

#define PF 4  // weight prefetch ring depth (ksteps)

__device__ __forceinline__ void hidden_layer32(const unsigned short* __restrict__ wp,
                                               const float* __restrict__ br,
                                               unsigned short* hT,
                                               int wf, int l, int li31, int lo5) {
  floatx16 acc[2][2];
  bias_init2x2(acc, br, wf, lo5);
  short8 ap[PF][2];
#pragma unroll
  for (int p = 0; p < PF; ++p) {
    ap[p][0] = *(const short8*)(wp + (long)((p * 8 + wf * 2 + 0) * 64 + l) * 8);
    ap[p][1] = *(const short8*)(wp + (long)((p * 8 + wf * 2 + 1) * 64 + l) * 8);
  }
#pragma unroll
  for (int ks = 0; ks < 16; ++ks) {
    short8 a0 = ap[ks % PF][0];
    short8 a1 = ap[ks % PF][1];
    if (ks + PF < 16) {
      ap[ks % PF][0] = *(const short8*)(wp + (long)(((ks + PF) * 8 + wf * 2 + 0) * 64 + l) * 8);
      ap[ks % PF][1] = *(const short8*)(wp + (long)(((ks + PF) * 8 + wf * 2 + 1) * 64 + l) * 8);
    }
    short8 b0 = *(const short8*)(hT + ((ks * 2 + 0) * 64 + l) * 8);
    short8 b1 = *(const short8*)(hT + ((ks * 2 + 1) * 64 + l) * 8);
    acc[0][0] = mfma32(a0, b0, acc[0][0]);
    acc[1][0] = mfma32(a1, b0, acc[1][0]);
    acc[0][1] = mfma32(a0, b1, acc[0][1]);
    acc[1][1] = mfma32(a1, b1, acc[1][1]);
  }
  __syncthreads();  // all reads of hT done before in-place overwrite
#pragma unroll
  for (int i = 0; i < 2; ++i)
#pragma unroll
    for (int o = 0; o < 2; ++o)
      store_tile(acc[i][o], hT, wf * 2 + i, o, li31, lo5);
  __syncthreads();
}

__global__ __launch_bounds__(256, 3) void k_mlp(
    const unsigned short* __restrict__ sa,
    const unsigned short* __restrict__ w1,
    const unsigned short* __restrict__ w2,
    const unsigned short* __restrict__ w3,
    const unsigned short* __restrict__ w4,
    const float* __restrict__ bias,
    const int* __restrict__ flag,
    void* __restrict__ outp) {
  __shared__ __attribute__((aligned(16))) unsigned short hT[16384];  // 32 KB
  const int tid = threadIdx.x;
  const int wf = tid >> 6, l = tid & 63, li31 = l & 31, lo5 = l >> 5;
  const int bb = blockIdx.x;  // 64-row batch tile
  const int e  = blockIdx.y;  // ensemble
  const float* brow = bias + e * 832;
  const bool isbf = (*flag != 0);

  // ---- layer 1: W1^T(256x64) * sa^T(64x64) -> h1^T in LDS ----
  {
    floatx16 acc[2][2];
    bias_init2x2(acc, brow, wf, lo5);
    short8 a[4][2], bfr[4][2];
#pragma unroll
    for (int ks = 0; ks < 4; ++ks) {
#pragma unroll
      for (int i = 0; i < 2; ++i)
        a[ks][i] = *(const short8*)(w1 + (long)e * 16384 +
                                    (long)((ks * 8 + wf * 2 + i) * 64 + l) * 8);
#pragma unroll
      for (int o = 0; o < 2; ++o)
        bfr[ks][o] = *(const short8*)(sa + (long)(((bb * 2 + o) * 4 + ks) * 64 + l) * 8);
    }
#pragma unroll
    for (int ks = 0; ks < 4; ++ks) {
      acc[0][0] = mfma32(a[ks][0], bfr[ks][0], acc[0][0]);
      acc[1][0] = mfma32(a[ks][1], bfr[ks][0], acc[1][0]);
      acc[0][1] = mfma32(a[ks][0], bfr[ks][1], acc[0][1]);
      acc[1][1] = mfma32(a[ks][1], bfr[ks][1], acc[1][1]);
    }
#pragma unroll
    for (int i = 0; i < 2; ++i)
#pragma unroll
      for (int o = 0; o < 2; ++o)
        store_tile(acc[i][o], hT, wf * 2 + i, o, li31, lo5);
    __syncthreads();
  }

  // ---- layers 2, 3 ----
  hidden_layer32(w2 + (long)e * 65536, brow + 256, hT, wf, l, li31, lo5);
  hidden_layer32(w3 + (long)e * 65536, brow + 512, hT, wf, l, li31, lo5);

  // ---- layer 4: W4^T(64x256) * h3^T(256x64); wave w: FT4=w&1, BT4=w>>1 ----
  const float* brow4 = brow + 768;
  const int FT4 = wf & 1, BT4 = wf >> 1;
  floatx16 acc4;
#pragma unroll
  for (int q = 0; q < 4; ++q) {
    const float4 bq = *(const float4*)(brow4 + FT4 * 32 + q * 8 + lo5 * 4);
    acc4[4 * q + 0] = bq.x;
    acc4[4 * q + 1] = bq.y;
    acc4[4 * q + 2] = bq.z;
    acc4[4 * q + 3] = bq.w;
  }
#pragma unroll
  for (int ks = 0; ks < 16; ++ks) {
    short8 a = *(const short8*)(w4 + (long)e * 16384 + (long)((ks * 2 + FT4) * 64 + l) * 8);
    short8 bfr = *(const short8*)(hT + ((ks * 2 + BT4) * 64 + l) * 8);
    acc4 = mfma32(a, bfr, acc4);
  }

  // ---- output ----
  const int batch = bb * 64 + BT4 * 32 + li31;
  const long nsbase = (long)(batch * NE + e) * 32;
  if (FT4 == 0) {
    if (isbf) {
      unsigned short* o16 = (unsigned short*)outp;
#pragma unroll
      for (int q = 0; q < 4; ++q) {
        unsigned d0 = pack_bf2(acc4[4 * q + 0], acc4[4 * q + 1]);
        unsigned d1 = pack_bf2(acc4[4 * q + 2], acc4[4 * q + 3]);
        *(unsigned long long*)(o16 + nsbase + q * 8 + lo5 * 4) =
            (unsigned long long)d0 | ((unsigned long long)d1 << 32);
      }
    } else {
      float* o32 = (float*)outp;
#pragma unroll
      for (int q = 0; q < 4; ++q)
        *(float4*)(o32 + nsbase + q * 8 + lo5 * 4) =
            make_float4(acc4[4 * q], acc4[4 * q + 1], acc4[4 * q + 2], acc4[4 * q + 3]);
    }
  } else if (lo5 == 0) {  // reward = feat 32: reg 0, lanes 0..31
    if (isbf) {
      unsigned u = __float_as_uint(acc4[0]) + 0x8000u;
      ((unsigned short*)outp)[OUT_NS_ELEMS + batch * NE + e] = (unsigned short)(u >> 16);
    } else {
      ((float*)outp)[OUT_NS_ELEMS + batch * NE + e] = acc4[0];
    }
  }
}

// ---------------------------------------------------------------------------
extern "C" void kernel_launch(void* const* d_in, const int* in_sizes, int n_in,
                              void* d_out, int out_size, void* d_ws, size_t ws_size,
                              hipStream_t stream) {
  const void* state  = d_in[0];
  const void* action = d_in[1];
  const void* W1 = d_in[2];
  const void* b1 = d_in[3];
  const void* W2 = d_in[4];
  const void* b2 = d_in[5];
  const void* W3 = d_in[6];
  const void* b3 = d_in[7];
  const void* W4 = d_in[8];
  const void* b4 = d_in[9];
  (void)in_sizes; (void)n_in; (void)out_size; (void)ws_size;

  char* ws = (char*)d_ws;
  int* flag              = (int*)(ws + 0);
  unsigned short* saP    = (unsigned short*)(ws + 256);        // 1,048,576 B
  unsigned short* w1P    = (unsigned short*)(ws + 1048832);    // 1,638,400 B
  unsigned short* w2P    = (unsigned short*)(ws + 2687232);    // 6,553,600 B
  unsigned short* w3P    = (unsigned short*)(ws + 9240832);    // 6,553,600 B
  unsigned short* w4P    = (unsigned short*)(ws + 15794432);   // 1,638,400 B
  float* biasP           = (float*)(ws + 17432832);            //   166,400 B
  // total ws use: 17,599,232 B

  k_detect<<<1, 256, 0, stream>>>((const unsigned*)W2, flag);
  k_pack<<<1719, 256, 0, stream>>>(state, action, W1, W2, W3, W4, b1, b2, b3, b4,
                                   flag, saP, w1P, w2P, w3P, w4P, biasP);
  k_mlp<<<dim3(128, 50), 256, 0, stream>>>(saP, w1P, w2P, w3P, w4P, biasP, flag, d_out);
}

// Round 5
// 252.473 us; speedup vs baseline: 1.2209x; 1.2209x over previous
//
#include <hip/hip_runtime.h>

// ---------------------------------------------------------------------------
// EnsembleTransitionMLP: fused 4-layer MLP over 50 ensembles, bf16 MFMA.
// Round 5 (revert R4's 32x32; back to R3 fragments + wave reshape):
//  - 256 thr / 4 waves, BM=128: each wave owns a 64-feat strip x ALL 128
//    batch (acc[4][8] = 128 regs). Weight fragments read exactly once per
//    block (R3 had 2x duplication) -> L2 weight traffic halved.
//  - __launch_bounds__(256,2): 256-reg budget -> depth-1 weight prefetch
//    ring + cached b-frags actually fit (R3's ring was silently dropped at
//    the 128-reg cap). 8 waves/CU, ILP-driven latency hiding.
//  - output via LDS transpose -> full-cacheline coalesced stores (R4's 8B
//    scatter caused 198MB write amplification; ideal is 27MB).
//  - rewards staged to d_ws coalesced; k_reward kernel does the [e][b] ->
//    [b][e] transpose (kills 410K scattered 2B RMW stores).
// Fragment layouts (16x16x32 bf16, same as R2/R3):
//   A: lane l holds A[m=l&15][k=(l>>4)*8+j]   (weights as W^T)
//   B: lane l holds B[k=(l>>4)*8+j][n=l&15]   (h^T: k=feat, n=batch)
//   C/D: lane l, reg r: feat=(l>>4)*4+r, batch=l&15
// ---------------------------------------------------------------------------

typedef __attribute__((ext_vector_type(8))) short short8;
typedef __attribute__((ext_vector_type(4))) float floatx4;

#define NE 50
#define NB 8192
#define OUT_NS_ELEMS (NB * NE * 32)
#define OSTRIDE 48  // shorts; 96B = 16B-aligned rows for b128 reads

__device__ __forceinline__ unsigned short f2bf_rne(float x) {
  unsigned u = __float_as_uint(x);
  u += 0x7fffu + ((u >> 16) & 1u);
  return (unsigned short)(u >> 16);
}
__device__ __forceinline__ float bf2f(unsigned short b) {
  return __uint_as_float(((unsigned)b) << 16);
}
__device__ __forceinline__ floatx4 mfma16(short8 a, short8 b, floatx4 c) {
  return __builtin_amdgcn_mfma_f32_16x16x32_bf16(a, b, c, 0, 0, 0);
}
// pack two f32 -> one dword of bf16 pair, round-half-up
__device__ __forceinline__ unsigned pack_bf2(float lo, float hi) {
  unsigned u0 = __float_as_uint(lo) + 0x8000u;
  unsigned u1 = __float_as_uint(hi) + 0x8000u;
  return __builtin_amdgcn_perm(u1, u0, 0x07060302u);  // [u0.hi16, u1.hi16]
}

// ---------------- dtype detection ----------------
__global__ void k_detect(const unsigned* __restrict__ w2raw, int* __restrict__ flag) {
  __shared__ int s_bad;
  if (threadIdx.x == 0) s_bad = 0;
  __syncthreads();
  bool bad = false;
  for (int i = threadIdx.x; i < 2048; i += 256) {
    unsigned word = w2raw[i * 797];
    unsigned short lo = (unsigned short)(word & 0xFFFFu);
    float f = bf2f(lo);
    if (!(fabsf(f) < 16.0f)) bad = true;
    if (lo == 0) bad = true;
  }
  if (bad) s_bad = 1;
  __syncthreads();
  if (threadIdx.x == 0) *flag = s_bad ? 0 : 1;  // 1 => bf16 inputs
}

__device__ __forceinline__ unsigned short load_bf(const void* p, long i, bool isbf) {
  if (isbf) return ((const unsigned short*)p)[i];
  return f2bf_rne(((const float*)p)[i]);
}
__device__ __forceinline__ float load_f(const void* p, long i, bool isbf) {
  if (isbf) return bf2f(((const unsigned short*)p)[i]);
  return ((const float*)p)[i];
}

// ---------------- mega pack (identical to R3) ----------------
// W pack layout per ensemble (B-fragment order):
//   elt = (((kt*NT + nt)*4 + kb)*16 + ni)*8 + j ; k = kt*32+kb*8+j ; n = nt*16+ni
__device__ void pack_w_panel(const void* __restrict__ src, unsigned short* __restrict__ dst,
                             bool isbf, int e, int kt, int K, int N, int NT, int perE,
                             unsigned short* lds) {
  const int t = threadIdx.x;
  const int Npad = NT * 16;
  const int NP = Npad + 10;
  for (int idx = t; idx < 32 * Npad; idx += 256) {
    int r = idx / Npad, c = idx - r * Npad;
    int k = kt * 32 + r;
    unsigned short v = 0;
    if (k < K && c < N) v = load_bf(src, (long)(e * K + k) * N + c, isbf);
    lds[r * NP + c] = v;
  }
  __syncthreads();
  for (int u = t; u < NT * 64; u += 256) {
    int nt = u >> 6, kb = (u >> 4) & 3, ni = u & 15;
    int n = nt * 16 + ni;
    unsigned v[4];
#pragma unroll
    for (int p = 0; p < 4; ++p) {
      unsigned lo = lds[(kb * 8 + 2 * p) * NP + n];
      unsigned hi = lds[(kb * 8 + 2 * p + 1) * NP + n];
      v[p] = lo | (hi << 16);
    }
    long off = (long)e * perE + ((long)((kt * NT + nt) * 64 + kb * 16 + ni)) * 8;
    *(uint4*)(dst + off) = make_uint4(v[0], v[1], v[2], v[3]);
  }
}

__global__ void k_pack(const void* __restrict__ state, const void* __restrict__ action,
                       const void* __restrict__ W1, const void* __restrict__ W2,
                       const void* __restrict__ W3, const void* __restrict__ W4,
                       const void* __restrict__ b1, const void* __restrict__ b2,
                       const void* __restrict__ b3, const void* __restrict__ b4,
                       const int* __restrict__ flag,
                       unsigned short* __restrict__ saP, unsigned short* __restrict__ w1P,
                       unsigned short* __restrict__ w2P, unsigned short* __restrict__ w3P,
                       unsigned short* __restrict__ w4P, float* __restrict__ biasP) {
  __shared__ unsigned short lds[32 * 266];  // 17,024 B
  const bool isbf = (*flag != 0);
  const int b = blockIdx.x;
  if (b < 400) {
    pack_w_panel(W2, w2P, isbf, b >> 3, b & 7, 256, 256, 16, 65536, lds);
  } else if (b < 800) {
    int bb = b - 400;
    pack_w_panel(W3, w3P, isbf, bb >> 3, bb & 7, 256, 256, 16, 65536, lds);
  } else if (b < 900) {
    int bb = b - 800;
    pack_w_panel(W1, w1P, isbf, bb >> 1, bb & 1, 40, 256, 16, 16384, lds);
  } else if (b < 1300) {
    int bb = b - 900;
    pack_w_panel(W4, w4P, isbf, bb >> 3, bb & 7, 256, 33, 3, 12288, lds);
  } else if (b < 1556) {
    // sa pack (B-frag units): addr(batch=mt*16+mi, k=kb*8+j) =
    //   (mt*128 + kb*16 + mi)*8 + j   (K padded 40->64)
    int u = (b - 1300) * 256 + threadIdx.x;  // < 65536
    int mi = u & 15, kb = (u >> 4) & 7, mt = u >> 7;
    int row = mt * 16 + mi;
    unsigned v[4] = {0u, 0u, 0u, 0u};
    if (kb < 4) {
#pragma unroll
      for (int p = 0; p < 4; ++p) {
        unsigned lo = load_bf(state, (long)row * 32 + kb * 8 + 2 * p, isbf);
        unsigned hi = load_bf(state, (long)row * 32 + kb * 8 + 2 * p + 1, isbf);
        v[p] = lo | (hi << 16);
      }
    } else if (kb == 4) {
#pragma unroll
      for (int p = 0; p < 4; ++p) {
        unsigned lo = load_bf(action, (long)row * 8 + 2 * p, isbf);
        unsigned hi = load_bf(action, (long)row * 8 + 2 * p + 1, isbf);
        v[p] = lo | (hi << 16);
      }
    }
    *(uint4*)(saP + (long)u * 8) = make_uint4(v[0], v[1], v[2], v[3]);
  } else {
    // bias: per e: [b1(256)][b2(256)][b3(256)][b4(48 zero-padded)]
    int gid = (b - 1556) * 256 + threadIdx.x;
    if (gid < NE * 816) {
      int e = gid / 816, r = gid - e * 816;
      float v = 0.0f;
      if (r < 256)      v = load_f(b1, e * 256 + r,         isbf);
      else if (r < 512) v = load_f(b2, e * 256 + (r - 256), isbf);
      else if (r < 768) v = load_f(b3, e * 256 + (r - 512), isbf);
      else { int q = r - 768; if (q < 33) v = load_f(b4, e * 33 + q, isbf); }
      biasP[gid] = v;
    }
  }
}

// ---------------- fused MLP ----------------
// hT in LDS (64KB), B-frag units for BM=128:
//   short addr(k,b) = ((k>>5)*8 + (b>>4))*512 + ((k>>3)&3)*128 + (b&15)*8 + (k&7)
// B-frag read (kt, bt): 16B at ((kt*8 + bt)*64 + l)*8.

__device__ __forceinline__ void store_tile16(const floatx4& a4, unsigned short* hT,
                                             int FT, int BT, int li, int g) {
  int k0 = FT * 16 + g * 4;
  unsigned d0 = pack_bf2(fmaxf(a4[0], 0.0f), fmaxf(a4[1], 0.0f));
  unsigned d1 = pack_bf2(fmaxf(a4[2], 0.0f), fmaxf(a4[3], 0.0f));
  int addr = ((k0 >> 5) * 8 + BT) * 512 + ((k0 >> 3) & 3) * 128 + li * 8 + (k0 & 7);
  *(unsigned long long*)(hT + addr) =
      (unsigned long long)d0 | ((unsigned long long)d1 << 32);
}

// wave wf owns feats [wf*64, wf*64+64) x all 128 batch: acc[4 ftiles][8 btiles]
__device__ __forceinline__ void hidden_layer(const unsigned short* __restrict__ wp,
                                             const float* __restrict__ br,
                                             unsigned short* hT,
                                             int wf, int l, int li, int g) {
  floatx4 acc[4][8];
#pragma unroll
  for (int ot = 0; ot < 4; ++ot) {
    const float4 bq = *(const float4*)(br + wf * 64 + ot * 16 + g * 4);
    floatx4 iv = {bq.x, bq.y, bq.z, bq.w};
#pragma unroll
    for (int bt = 0; bt < 8; ++bt) acc[ot][bt] = iv;
  }
  short8 a[4], an[4];
#pragma unroll
  for (int ot = 0; ot < 4; ++ot)
    a[ot] = *(const short8*)(wp + (long)((wf * 4 + ot) * 64 + l) * 8);
#pragma unroll
  for (int kt = 0; kt < 8; ++kt) {
    if (kt < 7) {
#pragma unroll
      for (int ot = 0; ot < 4; ++ot)
        an[ot] = *(const short8*)(wp + (long)(((kt + 1) * 16 + wf * 4 + ot) * 64 + l) * 8);
    }
#pragma unroll
    for (int bt = 0; bt < 8; ++bt) {
      short8 b = *(const short8*)(hT + ((kt * 8 + bt) * 64 + l) * 8);
#pragma unroll
      for (int ot = 0; ot < 4; ++ot)
        acc[ot][bt] = mfma16(a[ot], b, acc[ot][bt]);
    }
    if (kt < 7) {
#pragma unroll
      for (int ot = 0; ot < 4; ++ot) a[ot] = an[ot];
    }
  }
  __syncthreads();  // all reads of hT done before in-place overwrite
#pragma unroll
  for (int ot = 0; ot < 4; ++ot)
#pragma unroll
    for (int bt = 0; bt < 8; ++bt)
      store_tile16(acc[ot][bt], hT, wf * 4 + ot, bt, li, g);
  __syncthreads();
}

__global__ __launch_bounds__(256, 2) void k_mlp(
    const unsigned short* __restrict__ sa,
    const unsigned short* __restrict__ w1,
    const unsigned short* __restrict__ w2,
    const unsigned short* __restrict__ w3,
    const unsigned short* __restrict__ w4,
    const float* __restrict__ bias,
    const int* __restrict__ flag,
    float* __restrict__ rewardWS,
    void* __restrict__ outp) {
  __shared__ __attribute__((aligned(16))) unsigned short hT[32768];  // 64 KB
  const int tid = threadIdx.x;
  const int wf = tid >> 6, l = tid & 63, li = l & 15, g = l >> 4;
  const int bb = blockIdx.x;  // 128-row batch tile (64 tiles)
  const int e  = blockIdx.y;  // ensemble
  const float* brow = bias + e * 816;
  const bool isbf = (*flag != 0);

  // ---- layer 1: W1^T(256x64) * sa^T(64x128) -> h1^T in LDS ----
  {
    floatx4 acc[4][8];
#pragma unroll
    for (int ot = 0; ot < 4; ++ot) {
      const float4 bq = *(const float4*)(brow + wf * 64 + ot * 16 + g * 4);
      floatx4 iv = {bq.x, bq.y, bq.z, bq.w};
#pragma unroll
      for (int bt = 0; bt < 8; ++bt) acc[ot][bt] = iv;
    }
#pragma unroll
    for (int kt = 0; kt < 2; ++kt) {
      short8 a[4];
#pragma unroll
      for (int ot = 0; ot < 4; ++ot)
        a[ot] = *(const short8*)(w1 + (long)e * 16384 +
                                 (long)((kt * 16 + wf * 4 + ot) * 64 + l) * 8);
#pragma unroll
      for (int bt = 0; bt < 8; ++bt) {
        short8 b = *(const short8*)(sa + (long)((bb * 8 + bt) * 128 + kt * 64 + l) * 8);
#pragma unroll
        for (int ot = 0; ot < 4; ++ot)
          acc[ot][bt] = mfma16(a[ot], b, acc[ot][bt]);
      }
    }
#pragma unroll
    for (int ot = 0; ot < 4; ++ot)
#pragma unroll
      for (int bt = 0; bt < 8; ++bt)
        store_tile16(acc[ot][bt], hT, wf * 4 + ot, bt, li, g);
    __syncthreads();
  }

  // ---- layers 2, 3 ----
  hidden_layer(w2 + (long)e * 65536, brow + 256, hT, wf, l, li, g);
  hidden_layer(w3 + (long)e * 65536, brow + 512, hT, wf, l, li, g);

  // ---- layer 4: W4^T(48x256) * h3^T(256x128); wave wf owns btiles {2wf,2wf+1} ----
  const float* brow4 = brow + 768;
  floatx4 acc4[3][2];
#pragma unroll
  for (int ft = 0; ft < 3; ++ft) {
    const float4 bq = *(const float4*)(brow4 + ft * 16 + g * 4);
    floatx4 iv = {bq.x, bq.y, bq.z, bq.w};
    acc4[ft][0] = iv;
    acc4[ft][1] = iv;
  }
#pragma unroll
  for (int kt = 0; kt < 8; ++kt) {
    short8 a[3];
#pragma unroll
    for (int ft = 0; ft < 3; ++ft)
      a[ft] = *(const short8*)(w4 + (long)e * 12288 + (long)((kt * 3 + ft) * 64 + l) * 8);
#pragma unroll
    for (int bl = 0; bl < 2; ++bl) {
      short8 b = *(const short8*)(hT + ((kt * 8 + wf * 2 + bl) * 64 + l) * 8);
#pragma unroll
      for (int ft = 0; ft < 3; ++ft)
        acc4[ft][bl] = mfma16(a[ft], b, acc4[ft][bl]);
    }
  }

  // reward (feat 32 = ft2, g==0, reg 0) -> staged coalesced into ws[e][batch]
  if (g == 0) {
#pragma unroll
    for (int bl = 0; bl < 2; ++bl)
      rewardWS[(long)e * NB + bb * 128 + (wf * 2 + bl) * 16 + li] = acc4[2][bl][0];
  }

  __syncthreads();  // all hT reads done; reuse hT as output staging buffer
  // stage out^T tiles -> osta[batch][feat] (bf16, stride OSTRIDE)
#pragma unroll
  for (int ft = 0; ft < 2; ++ft) {
#pragma unroll
    for (int bl = 0; bl < 2; ++bl) {
      int batch = (wf * 2 + bl) * 16 + li;
      unsigned d0 = pack_bf2(acc4[ft][bl][0], acc4[ft][bl][1]);
      unsigned d1 = pack_bf2(acc4[ft][bl][2], acc4[ft][bl][3]);
      *(unsigned long long*)(hT + batch * OSTRIDE + ft * 16 + g * 4) =
          (unsigned long long)d0 | ((unsigned long long)d1 << 32);
    }
  }
  __syncthreads();

  // coalesced store: full 64B line per (batch,e)
  if (isbf) {
    unsigned short* o16 = (unsigned short*)outp;
#pragma unroll
    for (int p = 0; p < 2; ++p) {
      int batch = p * 64 + (tid >> 2);
      int chunk = tid & 3;  // 8 shorts each
      uint4 v = *(const uint4*)(hT + batch * OSTRIDE + chunk * 8);
      *(uint4*)(o16 + ((long)(bb * 128 + batch) * NE + e) * 32 + chunk * 8) = v;
    }
  } else {
    float* o32 = (float*)outp;
#pragma unroll
    for (int p = 0; p < 4; ++p) {
      int idx = p * 256 + tid;
      int batch = idx >> 3;
      int chunk = idx & 7;  // 4 floats each
      const unsigned short* s = hT + batch * OSTRIDE + chunk * 4;
      *(float4*)(o32 + ((long)(bb * 128 + batch) * NE + e) * 32 + chunk * 4) =
          make_float4(bf2f(s[0]), bf2f(s[1]), bf2f(s[2]), bf2f(s[3]));
    }
  }
}

// ---------------- reward transpose epilogue ----------------
__global__ void k_reward(const float* __restrict__ rw, const int* __restrict__ flag,
                         void* __restrict__ outp) {
  int id = blockIdx.x * 256 + threadIdx.x;
  if (id >= NB * NE) return;
  int b = id / NE, e = id - b * NE;
  float v = rw[(long)e * NB + b];
  if (*flag != 0) {
    unsigned u = __float_as_uint(v) + 0x8000u;
    ((unsigned short*)outp)[OUT_NS_ELEMS + id] = (unsigned short)(u >> 16);
  } else {
    ((float*)outp)[OUT_NS_ELEMS + id] = v;
  }
}

// ---------------------------------------------------------------------------
extern "C" void kernel_launch(void* const* d_in, const int* in_sizes, int n_in,
                              void* d_out, int out_size, void* d_ws, size_t ws_size,
                              hipStream_t stream) {
  const void* state  = d_in[0];
  const void* action = d_in[1];
  const void* W1 = d_in[2];
  const void* b1 = d_in[3];
  const void* W2 = d_in[4];
  const void* b2 = d_in[5];
  const void* W3 = d_in[6];
  const void* b3 = d_in[7];
  const void* W4 = d_in[8];
  const void* b4 = d_in[9];
  (void)in_sizes; (void)n_in; (void)out_size; (void)ws_size;

  char* ws = (char*)d_ws;
  int* flag              = (int*)(ws + 0);
  unsigned short* saP    = (unsigned short*)(ws + 256);        // 1,048,576 B
  unsigned short* w1P    = (unsigned short*)(ws + 1048832);    // 1,638,400 B
  unsigned short* w2P    = (unsigned short*)(ws + 2687232);    // 6,553,600 B
  unsigned short* w3P    = (unsigned short*)(ws + 9240832);    // 6,553,600 B
  unsigned short* w4P    = (unsigned short*)(ws + 15794432);   // 1,228,800 B
  float* biasP           = (float*)(ws + 17023232);            //   163,200 B
  float* rewardWS        = (float*)(ws + 17186432);            // 1,638,400 B
  // total ws use: 18,824,832 B

  k_detect<<<1, 256, 0, stream>>>((const unsigned*)W2, flag);
  k_pack<<<1716, 256, 0, stream>>>(state, action, W1, W2, W3, W4, b1, b2, b3, b4,
                                   flag, saP, w1P, w2P, w3P, w4P, biasP);
  k_mlp<<<dim3(64, 50), 256, 0, stream>>>(saP, w1P, w2P, w3P, w4P, biasP, flag,
                                          rewardWS, d_out);
  k_reward<<<(NB * NE + 255) / 256, 256, 0, stream>>>(rewardWS, flag, d_out);
}